// Round 11
// baseline (532.331 us; speedup 1.0000x reference)
//
#include <hip/hip_runtime.h>

#define N_NODES 50000
#define E_EDGES 262144

typedef __attribute__((ext_vector_type(8))) short bf16x8;
typedef __attribute__((ext_vector_type(4))) float f32x4;

union V16 { uint4 u; bf16x8 h; };

__device__ __forceinline__ unsigned rne_pack(float a, float b) {
  unsigned ua = __float_as_uint(a); ua += 0x7fffu + ((ua >> 16) & 1u);
  unsigned ub = __float_as_uint(b); ub += 0x7fffu + ((ub >> 16) & 1u);
  return (ua >> 16) | (ub & 0xffff0000u);
}
__device__ __forceinline__ float bflo(unsigned u) { return __uint_as_float(u << 16); }
__device__ __forceinline__ float bfhi(unsigned u) { return __uint_as_float(u & 0xffff0000u); }
// (bits(a)>>16) | (bits(b)&0xffff0000) in one v_perm_b32
__device__ __forceinline__ unsigned perm_pack(float a, float b) {
  return __builtin_amdgcn_perm(__float_as_uint(b), __float_as_uint(a), 0x07060302u);
}
__device__ __forceinline__ void async_gather16(const void* gptr, void* lptr) {
  __builtin_amdgcn_global_load_lds(
      (const __attribute__((address_space(1))) void*)gptr,
      (__attribute__((address_space(3))) void*)lptr, 16, 0, 0);
}

// ---- prep: node_repr fp32 -> bf16 (RNE) ----
__global__ void cvt_node_kernel(const float* __restrict__ x, unsigned short* __restrict__ y) {
  int i = (blockIdx.x * 256 + threadIdx.x) * 8;
  float4 f0 = *(const float4*)(x + i);
  float4 f1 = *(const float4*)(x + i + 4);
  uint4 o;
  o.x = rne_pack(f0.x, f0.y);
  o.y = rne_pack(f0.z, f0.w);
  o.z = rne_pack(f1.x, f1.y);
  o.w = rne_pack(f1.z, f1.w);
  *(uint4*)(y + i) = o;
}

// ---- prep: W1 (1024x512 row-major in->out) -> W1pp2 bf16, 16-B units laid out
// [step(8)][sq=s*4+quad(16)][col(512)], unit = W1[k0..k0+8)[col], k0=s*256+step*32+quad*8
__global__ void prep_w1pp2_kernel(const float* __restrict__ w1, unsigned short* __restrict__ w1pp2) {
  int t = blockIdx.x * 256 + threadIdx.x;  // 65536 units
  int step = t >> 13;
  int rem = t & 8191;
  int sq = rem >> 9;
  int col = rem & 511;
  int s = sq >> 2, qd = sq & 3;
  int k0 = s * 256 + step * 32 + qd * 8;
  float f[8];
#pragma unroll
  for (int i = 0; i < 8; ++i) f[i] = w1[(size_t)(k0 + i) * 512 + col];
  uint4 o;
  o.x = rne_pack(f[0], f[1]);
  o.y = rne_pack(f[2], f[3]);
  o.z = rne_pack(f[4], f[5]);
  o.w = rne_pack(f[6], f[7]);
  *(uint4*)(w1pp2 + (size_t)t * 8) = o;
}

// ---- prep: out[e][c] = b2[c] ----
__global__ void init_out_kernel(float* __restrict__ out, const float* __restrict__ b2) {
  int i = blockIdx.x * 256 + threadIdx.x;
  float2 v; v.x = b2[0]; v.y = b2[1];
  *(float2*)(out + (size_t)i * 2) = v;
}

// ---- main fused kernel: 512 threads (8 waves) = 64 edges x 256 cols.
//      4 LDS sections (hi,hj,a2,a3) of 32KB each; a2/a3 built cooperatively ONCE;
//      K-loop barrier-free, B streamed from L2 (wave pairs share a slice -> L1 dedup) ----
__global__ __launch_bounds__(512) void edge_mlp_kernel(
    const unsigned short* __restrict__ nodeb,  // [50000][256] bf16
    const unsigned short* __restrict__ w1pp2,  // repacked W1 (see prep)
    const int* __restrict__ src,
    const int* __restrict__ dst,
    const float* __restrict__ b1,
    const float* __restrict__ w2,   // [512][2] fp32
    float* __restrict__ out) {      // [E][2] fp32, pre-init with b2
  // section s at s*32768; unit (e,u): addr = e*512 + ((u ^ (e&7))<<4), u = step*4+quad
  __shared__ char smem[131072];

  const int tid = threadIdx.x;
  const int wid = tid >> 6;
  const int lane = tid & 63;
  const int quad = lane >> 4;
  const int l16 = lane & 15;
  const int bx = blockIdx.x;
  // XCD swizzle
  const int xc = bx & 7;
  const int t2 = bx >> 3;
  const int n_half = t2 & 1;              // 0..1 (256-col halves)
  const int m_idx = (t2 >> 1) * 8 + xc;   // 0..4095 (64-edge tiles)
  const int row0 = m_idx * 64;
  const int mh = wid >> 2;                // 0..1: edge half (32 edges)
  const int ns = wid & 3;                 // 0..3: 64-col slice (pairs wid, wid^4 share)
  const int n0 = n_half * 256 + ns * 64;

  const char* nodeB = (const char*)nodeb;
  const char* w1B = (const char*)w1pp2;

  // ---- B register-load offsets: (s*4+quad)*8192 + (n0+l16)*16 (+ step*131072) ----
  unsigned bOff[4];
#pragma unroll
  for (int s = 0; s < 4; ++s)
    bOff[s] = (unsigned)((s * 4 + quad) * 8192 + (n0 + l16) * 16);
  const char* w1s = w1B;

  f32x4 acc[2][4];
#pragma unroll
  for (int mt = 0; mt < 2; ++mt)
#pragma unroll
    for (int nt = 0; nt < 4; ++nt)
      acc[mt][nt] = (f32x4){0.f, 0.f, 0.f, 0.f};

  // ---- prologue: stage hi/hj (each half-wave reads one full 512-B node row) ----
  {
    const int ehc = tid >> 5;          // 0..15
    const int wsl = tid & 31;
#pragma unroll
    for (int c = 0; c < 4; ++c) {
      int e = c * 16 + ehc;
      unsigned uo = (unsigned)((wsl ^ (e & 7)) << 4);
      unsigned so = ((unsigned)src[row0 + e] << 9) + uo;
      unsigned dofs = ((unsigned)dst[row0 + e] << 9) + uo;
      async_gather16(nodeB + so, smem + c * 8192 + wid * 1024);
      async_gather16(nodeB + dofs, smem + 32768 + c * 8192 + wid * 1024);
    }
  }
  __syncthreads();

  // ---- cooperative build: a2 = |hi-hj|, a3 = hi*hj, 4 units/thread, once per block ----
#pragma unroll
  for (int k = 0; k < 4; ++k) {
    int p = k * 512 + tid;  // unit id: e = p>>5, u = p&31
    unsigned off = (unsigned)((p >> 5) * 512 + (((p & 31) ^ ((p >> 5) & 7)) << 4));
    V16 a, b;
    a.u = *(const uint4*)(smem + off);
    b.u = *(const uint4*)(smem + 32768 + off);
    const unsigned hw[4] = {a.u.x, a.u.y, a.u.z, a.u.w};
    const unsigned jw[4] = {b.u.x, b.u.y, b.u.z, b.u.w};
    unsigned d[4], pr[4];
#pragma unroll
    for (int w = 0; w < 4; ++w) {
      float i0 = bflo(hw[w]), i1 = bfhi(hw[w]);
      float j0 = bflo(jw[w]), j1 = bfhi(jw[w]);
      d[w] = perm_pack(i0 - j0, i1 - j1) & 0x7fff7fffu;
      pr[w] = perm_pack(i0 * j0, i1 * j1);
    }
    *(uint4*)(smem + 65536 + off) = make_uint4(d[0], d[1], d[2], d[3]);
    *(uint4*)(smem + 98304 + off) = make_uint4(pr[0], pr[1], pr[2], pr[3]);
  }
  __syncthreads();

  // ---- K-loop: barrier-free; all 4 sections are plain LDS A-operands ----
  const unsigned aBase = (unsigned)((mh * 32 + l16) * 512);  // + mt*16*512
  const unsigned aXor = (unsigned)(l16 & 7);
#pragma unroll 2
  for (int step = 0; step < 8; ++step) {
    V16 bf[4][4];
#pragma unroll
    for (int s = 0; s < 4; ++s)
#pragma unroll
      for (int nt = 0; nt < 4; ++nt)
        bf[s][nt].u = *(const uint4*)(w1s + bOff[s] + nt * 256);
    const unsigned sw = (((unsigned)(step * 4 + quad) ^ aXor) << 4);
    V16 af[2][4];
#pragma unroll
    for (int mt = 0; mt < 2; ++mt)
#pragma unroll
      for (int s = 0; s < 4; ++s)
        af[mt][s].u = *(const uint4*)(smem + s * 32768 + aBase + mt * 8192 + sw);
#pragma unroll
    for (int s = 0; s < 4; ++s)
#pragma unroll
      for (int mt = 0; mt < 2; ++mt)
#pragma unroll
        for (int nt = 0; nt < 4; ++nt)
          acc[mt][nt] = __builtin_amdgcn_mfma_f32_16x16x32_bf16(af[mt][s].h, bf[s][nt].h, acc[mt][nt], 0, 0, 0);
    w1s += 131072;
  }

  // ---- epilogue: bias + ReLU + W2, 16-lane shuffle reduce, atomic out ----
#pragma unroll
  for (int mt = 0; mt < 2; ++mt) {
    float pc0[4] = {0.f, 0.f, 0.f, 0.f};
    float pc1[4] = {0.f, 0.f, 0.f, 0.f};
#pragma unroll
    for (int nt = 0; nt < 4; ++nt) {
      int gc = n0 + nt * 16 + l16;
      float b1v = b1[gc];
      float w20 = w2[gc * 2 + 0];
      float w21 = w2[gc * 2 + 1];
#pragma unroll
      for (int r = 0; r < 4; ++r) {
        float v = fmaxf(acc[mt][nt][r] + b1v, 0.f);
        pc0[r] = fmaf(v, w20, pc0[r]);
        pc1[r] = fmaf(v, w21, pc1[r]);
      }
    }
#pragma unroll
    for (int r = 0; r < 4; ++r) {
      float s0 = pc0[r], s1 = pc1[r];
#pragma unroll
      for (int off = 1; off < 16; off <<= 1) {
        s0 += __shfl_xor(s0, off);
        s1 += __shfl_xor(s1, off);
      }
      int e = row0 + mh * 32 + mt * 16 + quad * 4 + r;  // C/D: row = quad*4 + r
      if (l16 == 0) unsafeAtomicAdd(&out[(size_t)e * 2 + 0], s0);
      if (l16 == 1) unsafeAtomicAdd(&out[(size_t)e * 2 + 1], s1);
    }
  }
}

extern "C" void kernel_launch(void* const* d_in, const int* in_sizes, int n_in,
                              void* d_out, int out_size, void* d_ws, size_t ws_size,
                              hipStream_t stream) {
  const float* node = (const float*)d_in[0];
  const int* src = (const int*)d_in[1];
  const int* dst = (const int*)d_in[2];
  const float* W1 = (const float*)d_in[3];
  const float* b1 = (const float*)d_in[4];
  const float* W2 = (const float*)d_in[5];
  const float* b2 = (const float*)d_in[6];
  float* out = (float*)d_out;

  unsigned short* nodeb = (unsigned short*)d_ws;                      // 25,600,000 B
  unsigned short* w1pp2 = (unsigned short*)((char*)d_ws + 25600000);  // 1,048,576 B

  cvt_node_kernel<<<6250, 256, 0, stream>>>(node, nodeb);
  prep_w1pp2_kernel<<<256, 256, 0, stream>>>(W1, w1pp2);
  init_out_kernel<<<1024, 256, 0, stream>>>(out, b2);
  edge_mlp_kernel<<<8192, 512, 0, stream>>>(nodeb, w1pp2, src, dst, b1, W2, out);
}